// Round 3
// baseline (349.874 us; speedup 1.0000x reference)
//
#include <hip/hip_runtime.h>
#include <math.h>

// GridNeRF fused hierarchical sampling + volume rendering. R3.
// N=65536 rays, NC=64 coarse, NF=128 fine, S=192 combined samples.
// TWO rays per wave (register-interleaved ILP); 4 waves/block => 8 rays/block.
// No __syncthreads: all LDS is wave-private; intra-wave DS ordering suffices.
//
// Sort strategy: combined sort == stable merge of two sorted lists.
//  - coarse_t sorted by construction; sorting the 128 u's sorts fine_t
//    (Finv monotone). Bitonic 128, 2 regs/lane, both rays interleaved.
//  - fine rank  = j + pos_j + 1      (pos_j = searchsorted bin, needed for
//    the interpolation anyway)
//  - coarse rank = i + cnt_i, cnt_i = #{pos_j < i} via LDS histogram of pos
//    + exclusive lane scan (replaces R2's 8-deep dependent LDS search).
//  - bijection is structural for any non-decreasing pos_j (pos monotone in u
//    by the fixed probe tree), so no cdf max-scan needed.

#define NRAYS 65536
#define NCC   64
#define NFF   128
#define SS    192

__global__ __launch_bounds__(256, 6)
void nerf_fused(const float* __restrict__ ro,  const float* __restrict__ rd,
                const float* __restrict__ cw,  const float* __restrict__ ct,
                const float* __restrict__ uu,  const float* __restrict__ col,
                const float* __restrict__ den, float* __restrict__ out)
{
    const int lane = threadIdx.x & 63;
    const int wv   = threadIdx.x >> 6;
    const int ray0 = blockIdx.x * 8 + wv * 2;
    const int sl0  = wv * 2;            // LDS slot per ray

    __shared__ float s_cdf [8][65];
    __shared__ float s_ct  [8][64];
    __shared__ float s_vals[8][256];    // sorted combined t + zero pad
    __shared__ int   s_hist[8][64];

    // ---------- Phase 0: loads + hist zero ----------
    float wt[2], tc[2];
    float2 u2[2];
    #pragma unroll
    for (int r = 0; r < 2; ++r) {
        const size_t ray = ray0 + r;
        wt[r] = cw[ray * NCC + lane] + 1e-5f;
        tc[r] = ct[ray * NCC + lane];
        u2[r] = *(const float2*)(uu + ray * NFF + 2 * lane);
        s_hist[sl0 + r][lane] = 0;
    }

    // ---------- Phase 1: weights -> normalized cdf (both rays interleaved) ----------
    float x0 = wt[0], x1 = wt[1];
    #pragma unroll
    for (int off = 1; off < 64; off <<= 1) {
        float y0 = __shfl_up(x0, off);
        float y1 = __shfl_up(x1, off);
        if (lane >= off) { x0 += y0; x1 += y1; }
    }
    float t0 = __shfl(x0, 63), t1 = __shfl(x1, 63);
    s_cdf[sl0][lane + 1]     = x0 / t0;
    s_cdf[sl0 + 1][lane + 1] = x1 / t1;
    if (lane == 0) { s_cdf[sl0][0] = 0.0f; s_cdf[sl0 + 1][0] = 0.0f; }
    s_ct[sl0][lane]     = tc[0];
    s_ct[sl0 + 1][lane] = tc[1];

    // ---------- Phase 2: bitonic sort of 128 u's, both rays interleaved ----------
    // element e = 2*lane + q; regs (a0,a1)=ray0, (b0,b1)=ray1
    float a0 = u2[0].x, a1 = u2[0].y;
    float b0 = u2[1].x, b1 = u2[1].y;
    #pragma unroll
    for (int k = 2; k <= 128; k <<= 1) {
        #pragma unroll
        for (int j = k >> 1; j >= 1; j >>= 1) {
            bool up = (((lane << 1) & k) == 0);
            if (j == 1) {
                float m0 = fminf(a0, a1), M0 = fmaxf(a0, a1);
                float m1 = fminf(b0, b1), M1 = fmaxf(b0, b1);
                a0 = up ? m0 : M0;  a1 = up ? M0 : m0;
                b0 = up ? m1 : M1;  b1 = up ? M1 : m1;
            } else {
                const int m = j >> 1;
                bool keepmin = (((lane & m) == 0) == up);
                float pa0 = __shfl_xor(a0, m), pa1 = __shfl_xor(a1, m);
                float pb0 = __shfl_xor(b0, m), pb1 = __shfl_xor(b1, m);
                a0 = keepmin ? fminf(a0, pa0) : fmaxf(a0, pa0);
                a1 = keepmin ? fminf(a1, pa1) : fmaxf(a1, pa1);
                b0 = keepmin ? fminf(b0, pb0) : fmaxf(b0, pb0);
                b1 = keepmin ? fminf(b1, pb1) : fmaxf(b1, pb1);
            }
        }
    }

    // ---------- Phase 3: interp + fine scatter + pos histogram (4 indep chains) ----------
    #pragma unroll
    for (int r = 0; r < 2; ++r) {
        const int sl = sl0 + r;
        const float* cdfp = s_cdf[sl];
        const float* ctp  = s_ct[sl];
        float us[2];
        us[0] = r ? b0 : a0;
        us[1] = r ? b1 : a1;
        #pragma unroll
        for (int q = 0; q < 2; ++q) {
            float u = us[q];
            int pos = 0; float cb = 0.0f;
            #pragma unroll
            for (int st = 32; st >= 1; st >>= 1) {
                int np = pos + st;                 // in [1,63]
                float cv = cdfp[np];
                bool ok = (cv <= u);
                pos = ok ? np : pos;
                cb  = ok ? cv : cb;
            }
            int above = (pos + 1 < 63) ? (pos + 1) : 63;
            float ca = cdfp[above];
            float tb = ctp[pos], ta = ctp[above];
            float dnm = ca - cb;
            dnm = (dnm < 1e-5f) ? 1.0f : dnm;
            float fval = tb + ((u - cb) / dnm) * (ta - tb);
            s_vals[sl][2 * lane + q + pos + 1] = fval;   // fine merge rank
            atomicAdd(&s_hist[sl][pos], 1);
        }
    }

    // ---------- Phase 4: coarse merge rank via hist prefix + scatter ----------
    int h0 = s_hist[sl0][lane];
    int h1 = s_hist[sl0 + 1][lane];
    int i0 = h0, i1 = h1;                          // inclusive scan
    #pragma unroll
    for (int off = 1; off < 64; off <<= 1) {
        int y0 = __shfl_up(i0, off);
        int y1 = __shfl_up(i1, off);
        if (lane >= off) { i0 += y0; i1 += y1; }
    }
    int c0 = __shfl_up(i0, 1), c1 = __shfl_up(i1, 1);
    if (lane == 0) { c0 = 0; c1 = 0; }             // exclusive: cnt_i
    s_vals[sl0][lane + c0]     = tc[0];
    s_vals[sl0 + 1][lane + c1] = tc[1];
    s_vals[sl0][192 + lane]     = 0.0f;            // pad: keeps sums NaN-free
    s_vals[sl0 + 1][192 + lane] = 0.0f;

    // ---------- Phase 5: volume rendering (sequential epilogues, cap liveness) ----------
    #pragma unroll
    for (int r = 0; r < 2; ++r) {
        const int sl = sl0 + r;
        const size_t ray = ray0 + r;

        float4 sv = *(const float4*)&s_vals[sl][4 * lane];
        float v[4] = {sv.x, sv.y, sv.z, sv.w};

        float dx = rd[ray * 3 + 0], dy = rd[ray * 3 + 1], dz = rd[ray * 3 + 2];
        float ox = ro[ray * 3 + 0], oy = ro[ray * 3 + 1], oz = ro[ray * 3 + 2];
        float nrm = sqrtf(dx * dx + dy * dy + dz * dz);

        const bool active = lane < 48;
        float tnext = __shfl_down(v[0], 1);        // lane48 pad=0, masked below
        float dd[4];
        dd[0] = v[1] - v[0];
        dd[1] = v[2] - v[1];
        dd[2] = v[3] - v[2];
        dd[3] = (lane == 47) ? 1e10f : (tnext - v[3]);

        float4 dn4 = make_float4(0.f, 0.f, 0.f, 0.f);
        if (active) dn4 = *(const float4*)(den + ray * SS + 4 * lane);
        float dnv[4] = {dn4.x, dn4.y, dn4.z, dn4.w};

        float aa[4], ff[4];
        #pragma unroll
        for (int s = 0; s < 4; ++s) {
            float al = active ? (1.0f - expf(-dnv[s] * (dd[s] * nrm))) : 0.0f;
            aa[s] = al;
            ff[s] = active ? (1.0f - al + 1e-10f) : 1.0f;
        }

        if (active) {
            float* fp = out + (size_t)5 * NRAYS + ray * (SS * 3) + 12 * lane;
            float4 p0 = make_float4(ox + dx * v[0], oy + dy * v[0], oz + dz * v[0], ox + dx * v[1]);
            float4 p1 = make_float4(oy + dy * v[1], oz + dz * v[1], ox + dx * v[2], oy + dy * v[2]);
            float4 p2 = make_float4(oz + dz * v[2], ox + dx * v[3], oy + dy * v[3], oz + dz * v[3]);
            *(float4*)(fp + 0) = p0;
            *(float4*)(fp + 4) = p1;
            *(float4*)(fp + 8) = p2;
        }

        float pr1 = ff[0], pr2 = ff[0] * ff[1], pr3 = pr2 * ff[2];
        float sx = pr3 * ff[3];
        #pragma unroll
        for (int off = 1; off < 64; off <<= 1) {
            float y = __shfl_up(sx, off);
            if (lane >= off) sx *= y;
        }
        float excl = __shfl_up(sx, 1);
        if (lane == 0) excl = 1.0f;
        float w0 = aa[0] * excl;
        float w1 = aa[1] * (excl * pr1);
        float w2 = aa[2] * (excl * pr2);
        float w3 = aa[3] * (excl * pr3);

        float4 cc0 = make_float4(0.f,0.f,0.f,0.f), cc1 = cc0, cc2 = cc0;
        if (active) {
            const float* cp = col + ray * (SS * 3) + 12 * lane;
            cc0 = *(const float4*)(cp + 0);
            cc1 = *(const float4*)(cp + 4);
            cc2 = *(const float4*)(cp + 8);
        }
        float rr  = w0 * cc0.x + w1 * cc0.w + w2 * cc1.z + w3 * cc2.y;
        float gg  = w0 * cc0.y + w1 * cc1.x + w2 * cc1.w + w3 * cc2.z;
        float bb  = w0 * cc0.z + w1 * cc1.y + w2 * cc2.x + w3 * cc2.w;
        float dep = w0 * v[0] + w1 * v[1] + w2 * v[2] + w3 * v[3];
        float opa = w0 + w1 + w2 + w3;

        #pragma unroll
        for (int off = 32; off >= 1; off >>= 1) {
            rr  += __shfl_xor(rr,  off);
            gg  += __shfl_xor(gg,  off);
            bb  += __shfl_xor(bb,  off);
            dep += __shfl_xor(dep, off);
            opa += __shfl_xor(opa, off);
        }
        if (lane == 0) {
            out[ray * 3 + 0] = rr;
            out[ray * 3 + 1] = gg;
            out[ray * 3 + 2] = bb;
            out[(size_t)3 * NRAYS + ray] = dep;
            out[(size_t)4 * NRAYS + ray] = opa;
        }
    }
}

extern "C" void kernel_launch(void* const* d_in, const int* in_sizes, int n_in,
                              void* d_out, int out_size, void* d_ws, size_t ws_size,
                              hipStream_t stream) {
    const float* ro  = (const float*)d_in[0];
    const float* rd  = (const float*)d_in[1];
    const float* cw  = (const float*)d_in[2];
    const float* ct  = (const float*)d_in[3];
    const float* uu  = (const float*)d_in[4];
    const float* col = (const float*)d_in[5];
    const float* den = (const float*)d_in[6];
    float* out = (float*)d_out;
    (void)in_sizes; (void)n_in; (void)out_size; (void)d_ws; (void)ws_size;
    nerf_fused<<<NRAYS / 8, 256, 0, stream>>>(ro, rd, cw, ct, uu, col, den, out);
}